// Round 10
// baseline (4223.499 us; speedup 1.0000x reference)
//
#include <hip/hip_runtime.h>
#include <stdint.h>

typedef unsigned short u16;
typedef uint32_t u32;
typedef __attribute__((ext_vector_type(8))) short short8;
typedef __attribute__((ext_vector_type(4))) float floatx4;
typedef __attribute__((ext_vector_type(4))) int int4v;

constexpr int BB = 128;     // batch
constexpr int TT = 64;      // time steps
constexpr int CC = 66;      // frame channels
constexpr int CPAD = 96;    // C padded to multiple of 32 (MFMA K-chunk)
constexpr int SS = 512;     // hidden
constexpr int NGATE = 1536; // 3*S
constexpr int NGRP = 8;     // batch groups (16 batches each)
constexpr int GBLK = 16;    // blocks per group (s-split by 32)
constexpr int GS = 16 * SS; // per-group state slab elements (16 x 512)

__device__ __forceinline__ u16 f2bf(float f) {
    u32 u = __float_as_uint(f);
    u32 r = (u + 0x7fffu + ((u >> 16) & 1u)) >> 16;
    return (u16)r;
}
__device__ __forceinline__ float bf2f(u16 h) {
    return __uint_as_float(((u32)h) << 16);
}
__device__ __forceinline__ float sigm(float x) { return 1.f / (1.f + __expf(-x)); }
__device__ __forceinline__ float tanh_f(float x) { return 1.f - 2.f / (1.f + __expf(2.f * x)); }

// ---- system-coherent (MALL) primitives: bounded-latency cross-XCD path. ----
__device__ __forceinline__ void st128_cc(u16* p, short8 v) {
    asm volatile("global_store_dwordx4 %0, %1, off sc0 sc1"
                 :: "v"(p), "v"(v) : "memory");
}
__device__ __forceinline__ void ld128_cc(const u16* p, short8& d) {
    asm volatile("global_load_dwordx4 %0, %1, off sc0 sc1"
                 : "=v"(d) : "v"(p));
}
__device__ __forceinline__ void stflag_cc(int* p, int v) {
    asm volatile("global_store_dword %0, %1, off sc0 sc1"
                 :: "v"(p), "v"(v) : "memory");
}
__device__ __forceinline__ void vm_drain() {
    asm volatile("s_waitcnt vmcnt(0)" ::: "memory");
}
__device__ __forceinline__ void lds_drain() {
    asm volatile("s_waitcnt lgkmcnt(0)" ::: "memory");
}

__device__ __forceinline__ void set_flag(int* f, int v) {
    if ((threadIdx.x & 63) == 0) stflag_cc(f, v);
}

// ---------------------------------------------------------------------------
// Packed-flag combined wait.  Flag sets are 32 CONTIGUOUS ints (128 B = 2
// cachelines).  Every lane loads dwordx4 over the 4 lines of {f0,f1}
// (256 B/poll vs round 9's 4 KB), with s_sleep(8) backoff and caching:
// once a wait at target t succeeds we know min(flags) >= t and skip future
// waits with tgt <= t without issuing any loads.
// ---------------------------------------------------------------------------
__device__ __forceinline__ void wait2p(const int* __restrict__ f0, int t0,
                                       const int* __restrict__ f1, int t1,
                                       int& c0, int& c1) {
    if (c0 >= t0 && c1 >= t1) return;
    const int q = threadIdx.x & 15;
    const int* p = (q < 8) ? (f0 + q * 4) : (f1 + (q - 8) * 4);
    const int tgt = (q < 8) ? t0 : t1;
    for (;;) {
        int4v v;
        asm volatile("global_load_dwordx4 %0, %1, off sc0 sc1\n\t"
                     "s_waitcnt vmcnt(0)"
                     : "=v"(v) : "v"(p) : "memory");
        int m = v[0] < v[1] ? v[0] : v[1];
        int m2 = v[2] < v[3] ? v[2] : v[3];
        m = m < m2 ? m : m2;
        if (__all(m >= tgt)) break;
        __builtin_amdgcn_s_sleep(8);
    }
    if (t0 > c0) c0 = t0;
    if (t1 > c1) c1 = t1;
    asm volatile("" ::: "memory");
}

// ---------------------------------------------------------------------------
// prep1: bf16 conversion of x (padded to 96), the 4 GRU weight matrices,
// and Ws -> bf16 [80][512] (c-padded) for the MFMA frames epilogue.
// ---------------------------------------------------------------------------
__global__ void prep1_kernel(const float* __restrict__ x,
                             const float* __restrict__ Wih0,
                             const float* __restrict__ Whh0,
                             const float* __restrict__ Wih1,
                             const float* __restrict__ Whh1,
                             const float* __restrict__ Ws,
                             u16* __restrict__ xbf, u16* __restrict__ wi0,
                             u16* __restrict__ wh0, u16* __restrict__ wi1,
                             u16* __restrict__ wh1, u16* __restrict__ wsb)
{
    const int N_xbf = BB * TT * CPAD;
    const int N_wi0 = NGATE * CPAD;
    const int N_whh = NGATE * SS;
    const int N_wsb = 80 * SS;
    const long total = (long)N_xbf + N_wi0 + 3L * N_whh + N_wsb;
    for (long i = (long)blockIdx.x * blockDim.x + threadIdx.x; i < total;
         i += (long)gridDim.x * blockDim.x) {
        long idx = i;
        if (idx < N_xbf) {
            int c = idx % CPAD; int bt = idx / CPAD;
            float v = (c < CC) ? x[(long)bt * CC + c] : 0.f;
            xbf[idx] = f2bf(v); continue;
        }
        idx -= N_xbf;
        if (idx < N_wi0) {
            int c = idx % CPAD; int n = idx / CPAD;
            float v = (c < CC) ? Wih0[(long)n * CC + c] : 0.f;
            wi0[idx] = f2bf(v); continue;
        }
        idx -= N_wi0;
        if (idx < N_whh) { wh0[idx] = f2bf(Whh0[idx]); continue; }
        idx -= N_whh;
        if (idx < N_whh) { wi1[idx] = f2bf(Wih1[idx]); continue; }
        idx -= N_whh;
        if (idx < N_whh) { wh1[idx] = f2bf(Whh1[idx]); continue; }
        idx -= N_whh;
        {
            int s = idx % SS; int c = idx / SS;
            wsb[idx] = (c < CC) ? f2bf(Ws[(long)c * SS + s]) : (u16)0;
        }
    }
}

// ---------------------------------------------------------------------------
// prep2: M = Wih0[:, :66] @ Ws (bf16); c0vec = Wih0 @ bs; gi0i = x_last@Wih0^T
// ---------------------------------------------------------------------------
__global__ void prep2_kernel(const float* __restrict__ x,
                             const float* __restrict__ Wih0,
                             const float* __restrict__ Ws,
                             const float* __restrict__ bs,
                             u16* __restrict__ Mbf, float* __restrict__ c0vec,
                             float* __restrict__ gi0i)
{
    const long NM = (long)NGATE * SS;
    const long NC = NGATE;
    const long NG = (long)BB * NGATE;
    const long total = NM + NC + NG;
    for (long i = (long)blockIdx.x * blockDim.x + threadIdx.x; i < total;
         i += (long)gridDim.x * blockDim.x) {
        long idx = i;
        if (idx < NM) {
            int s = idx % SS; int g = idx / SS;
            float acc = 0.f;
            for (int c = 0; c < CC; ++c)
                acc += Wih0[(long)g * CC + c] * Ws[(long)c * SS + s];
            Mbf[idx] = f2bf(acc); continue;
        }
        idx -= NM;
        if (idx < NC) {
            int g = idx;
            float acc = 0.f;
            for (int c = 0; c < CC; ++c) acc += Wih0[(long)g * CC + c] * bs[c];
            c0vec[g] = acc; continue;
        }
        idx -= NC;
        {
            int g = idx % NGATE; int b = idx / NGATE;
            float acc = 0.f;
            const float* xl = x + ((long)b * TT + (TT - 1)) * CC;
            for (int c = 0; c < CC; ++c) acc += xl[c] * Wih0[(long)g * CC + c];
            gi0i[idx] = acc;
        }
    }
}

// ---------------------------------------------------------------------------
// A-fragment direct load: 16 coherent dwordx4 per K=512 GEMM into registers.
// ---------------------------------------------------------------------------
__device__ __forceinline__ void load_afrags(const u16* __restrict__ st,
                                            int l15, int quad, short8* a) {
#pragma unroll
    for (int kc = 0; kc < 16; ++kc)
        ld128_cc(st + (long)l15 * SS + kc * 32 + quad * 8, a[kc]);
}

#define MFMA_BF16(a, wp, acc) \
    acc = __builtin_amdgcn_mfma_f32_16x16x32_bf16(a, *(const short8*)(wp), acc, 0, 0, 0)

__device__ __forceinline__ void mm3_reg(const short8* a,
                                        const u16* __restrict__ w0,
                                        const u16* __restrict__ w1,
                                        const u16* __restrict__ w2,
                                        floatx4& A0, floatx4& A1, floatx4& A2) {
#pragma unroll
    for (int kc = 0; kc < 16; ++kc) {
        const int k = kc << 5;
        MFMA_BF16(a[kc], w0 + k, A0);
        MFMA_BF16(a[kc], w1 + k, A1);
        MFMA_BF16(a[kc], w2 + k, A2);
    }
}

template <int K>
__device__ __forceinline__ void mm3_g(const u16* __restrict__ aP,
                                      const u16* __restrict__ w0,
                                      const u16* __restrict__ w1,
                                      const u16* __restrict__ w2,
                                      floatx4& A0, floatx4& A1, floatx4& A2) {
#pragma unroll
    for (int k = 0; k < K; k += 32) {
        short8 a = *(const short8*)(aP + k);
        MFMA_BF16(a, w0 + k, A0);
        MFMA_BF16(a, w1 + k, A1);
        MFMA_BF16(a, w2 + k, A2);
    }
}

// ---------------------------------------------------------------------------
// Persistent kernel, wave-decoupled dataflow.  grp = blk&7, rank = blk>>3.
// Waves 0,1 = layer-0 (s-sub 0/1), waves 2,3 = layer-1.  Data AND flags on
// the sc0sc1 system-coherent path; flags packed (128 B/set) with cached,
// backoff polling.  State stores coalesced via per-wave LDS repack.
// ---------------------------------------------------------------------------
__global__ __launch_bounds__(256, 1) void persist_kernel(
    const u16* __restrict__ xbf,
    const u16* __restrict__ wi0, const u16* __restrict__ wh0,
    const u16* __restrict__ wi1, const u16* __restrict__ wh1,
    const u16* __restrict__ Mbf,
    const float* __restrict__ bih0, const float* __restrict__ bhh0,
    const float* __restrict__ bih1, const float* __restrict__ bhh1,
    const float* __restrict__ c0vec, const float* __restrict__ gi0i,
    const float* __restrict__ Wt, const float* __restrict__ bt,
    u16* __restrict__ h0buf,   // [NGRP][4][16][512]
    u16* __restrict__ h1buf,   // [NGRP][2][16][512]
    u16* __restrict__ tstage,  // [NGRP][2][16][512]
    u16* __restrict__ temps,   // [64][128][512] (cached; read by frames)
    int* __restrict__ gflags)  // [NGRP][1024]: f0 = ints 0..31, f1 = 256..287
{
    __shared__ __align__(16) u16 tile[4][2][256];   // [wave][h/t][16x16]

    const int tid = threadIdx.x;
    const int wave = tid >> 6, lane = tid & 63;
    const int l15 = lane & 15, quad = lane >> 4;
    const int grp = blockIdx.x & 7, rank = blockIdx.x >> 3;
    const int b0g = grp * 16;
    const int wsub = wave & 1;
    const int sg0 = rank * 32 + wsub * 16;        // wave's 16-col s base
    const int sg = sg0 + l15;
    const bool l0w = wave < 2;

    u16* const h0g = h0buf + (long)grp * 4 * GS;
    u16* const h1g = h1buf + (long)grp * 2 * GS;
    u16* const tsg = tstage + (long)grp * 2 * GS;
    int* const f0 = gflags + grp * 1024;          // 32 contiguous ints
    int* const f1 = f0 + 256;                     // 1 KB away, own lines
    const int myflag = rank * 2 + wsub;

    // ---- per-thread constants & register state ----
    float bir, biz, bin, bhn;
    float c0r = 0.f, c0z = 0.f, c0n = 0.f;
    float hf[4] = {0.f, 0.f, 0.f, 0.f};
    float gi[12];
    float wt[32]; float btv = 0.f;
    u32 wreg[4][16];
#pragma unroll
    for (int r = 0; r < 4; ++r)
#pragma unroll
        for (int i = 0; i < 16; ++i) wreg[r][i] = 0u;

    if (l0w) {
        bir = bih0[sg] + bhh0[sg];
        biz = bih0[512 + sg] + bhh0[512 + sg];
        bin = bih0[1024 + sg];
        bhn = bhh0[1024 + sg];
        c0r = c0vec[sg]; c0z = c0vec[512 + sg]; c0n = c0vec[1024 + sg];
#pragma unroll
        for (int g3 = 0; g3 < 3; ++g3)
#pragma unroll
            for (int r = 0; r < 4; ++r)
                gi[g3 * 4 + r] =
                    gi0i[(long)(b0g + quad * 4 + r) * NGATE + g3 * 512 + sg];
    } else {
        bir = bih1[sg] + bhh1[sg];
        biz = bih1[512 + sg] + bhh1[512 + sg];
        bin = bih1[1024 + sg];
        bhn = bhh1[1024 + sg];
#pragma unroll
        for (int j = 0; j < 32; ++j) wt[j] = Wt[j];
        btv = bt[0];
    }

    const u16 *wiR, *wiZ, *wiN, *whR, *whZ, *whN, *mR, *mZ, *mN;
    if (l0w) {
        wiR = wi0 + (long)sg * CPAD + quad * 8;
        wiZ = wi0 + (long)(512 + sg) * CPAD + quad * 8;
        wiN = wi0 + (long)(1024 + sg) * CPAD + quad * 8;
        whR = wh0 + (long)sg * SS + quad * 8;
        whZ = wh0 + (long)(512 + sg) * SS + quad * 8;
        whN = wh0 + (long)(1024 + sg) * SS + quad * 8;
        mR = Mbf + (long)sg * SS + quad * 8;
        mZ = Mbf + (long)(512 + sg) * SS + quad * 8;
        mN = Mbf + (long)(1024 + sg) * SS + quad * 8;
    } else {
        wiR = wi1 + (long)sg * SS + quad * 8;
        wiZ = wi1 + (long)(512 + sg) * SS + quad * 8;
        wiN = wi1 + (long)(1024 + sg) * SS + quad * 8;
        whR = wh1 + (long)sg * SS + quad * 8;
        whZ = wh1 + (long)(512 + sg) * SS + quad * 8;
        whN = wh1 + (long)(1024 + sg) * SS + quad * 8;
        mR = mZ = mN = nullptr;
    }

    // coalesced-store lane roles (lanes 0..31): row, half
    const int srow = lane >> 1, shalf = lane & 1;
    u16* const myTileH = &tile[wave][0][0];
    u16* const myTileT = &tile[wave][1][0];

    short8 fa[16], fb[16];
    int c0 = 0, c1 = 0;   // cached lower bounds of min(f0), min(f1)
    if (l0w) {
        // ========== layer-0 wave: encoder t=0..62 ==========
#pragma clang loop unroll(disable)
        for (int t = 0; t < 63; ++t) {
            floatx4 aR = {0,0,0,0}, aZ = aR, aNI = aR, aNH = aR;
            const u16* aP =
                xbf + ((long)(b0g + l15) * TT + t) * CPAD + quad * 8;
            mm3_g<CPAD>(aP, wiR, wiZ, wiN, aR, aZ, aNI);
            wait2p(f0, t, f1, t - 3, c0, c1);   // data ready + depth-4 guard
            load_afrags(h0g + (long)(t & 3) * GS, l15, quad, fa);
            vm_drain();
            mm3_reg(fa, whR, whZ, whN, aR, aZ, aNH);
#pragma unroll
            for (int r = 0; r < 4; ++r) {
                float rr = sigm(aR[r] + bir);
                float zz = sigm(aZ[r] + biz);
                float nn = tanh_f(aNI[r] + bin + rr * (aNH[r] + bhn));
                float hv = (1.f - zz) * nn + zz * hf[r];
                hf[r] = hv;
                myTileH[(quad * 4 + r) * 16 + l15] = f2bf(hv);
            }
            lds_drain();
            if (lane < 32) {
                short8 v = *(const short8*)(myTileH + srow * 16 + shalf * 8);
                st128_cc(h0g + (long)((t + 1) & 3) * GS +
                         (long)srow * SS + sg0 + shalf * 8, v);
            }
            vm_drain();
            set_flag(f0 + myflag, t + 1);
        }
        // ========== layer-0 wave: decoder d=0..63 ==========
#pragma clang loop unroll(disable)
        for (int d = 0; d < 64; ++d) {
            const int t = 63 + d;
            wait2p(f0, t, f1, (d > 0) ? t : 60, c0, c1);
            load_afrags(h0g + (long)(t & 3) * GS, l15, quad, fa);
            if (d > 0)
                load_afrags(tsg + (long)((d - 1) & 1) * GS, l15, quad, fb);
            vm_drain();
            if (d > 0) {   // gi(d) = gi(d-1) + M @ temp(d-1) + c0
                floatx4 tR = {0,0,0,0}, tZ = tR, tN = tR;
                mm3_reg(fb, mR, mZ, mN, tR, tZ, tN);
#pragma unroll
                for (int r = 0; r < 4; ++r) {
                    gi[r] += tR[r] + c0r;
                    gi[4 + r] += tZ[r] + c0z;
                    gi[8 + r] += tN[r] + c0n;
                }
            }
            floatx4 hR = {0,0,0,0}, hZ = hR, hN4 = hR;
            mm3_reg(fa, whR, whZ, whN, hR, hZ, hN4);
#pragma unroll
            for (int r = 0; r < 4; ++r) {
                float rr = sigm(gi[r] + hR[r] + bir);
                float zz = sigm(gi[4 + r] + hZ[r] + biz);
                float nn = tanh_f(gi[8 + r] + bin + rr * (hN4[r] + bhn));
                float hv = (1.f - zz) * nn + zz * hf[r];
                hf[r] = hv;
                myTileH[(quad * 4 + r) * 16 + l15] = f2bf(hv);
            }
            lds_drain();
            if (lane < 32) {
                short8 v = *(const short8*)(myTileH + srow * 16 + shalf * 8);
                st128_cc(h0g + (long)((t + 1) & 3) * GS +
                         (long)srow * SS + sg0 + shalf * 8, v);
            }
            vm_drain();
            set_flag(f0 + myflag, t + 1);
        }
    } else {
        // ========== layer-1 wave: u = 0..126 ==========
#pragma clang loop unroll(disable)
        for (int u = 0; u < 127; ++u) {
            const bool dec = (u >= 63);
            const int d = u - 63;
            wait2p(f0, u + 1, f1, u, c0, c1);
            load_afrags(h0g + (long)((u + 1) & 3) * GS, l15, quad, fa);
            load_afrags(h1g + (long)(u & 1) * GS, l15, quad, fb);
            vm_drain();
            floatx4 aR = {0,0,0,0}, aZ = aR, aNI = aR, aNH = aR;
            mm3_reg(fa, wiR, wiZ, wiN, aR, aZ, aNI);
            mm3_reg(fb, whR, whZ, whN, aR, aZ, aNH);
#pragma unroll
            for (int r = 0; r < 4; ++r) {
                float rr = sigm(aR[r] + bir);
                float zz = sigm(aZ[r] + biz);
                float nn = tanh_f(aNI[r] + bin + rr * (aNH[r] + bhn));
                float hv = (1.f - zz) * nn + zz * hf[r];
                hf[r] = hv;
                u16 hb = f2bf(hv);
                myTileH[(quad * 4 + r) * 16 + l15] = hb;
#pragma unroll
                for (int i = 0; i < 15; ++i)
                    wreg[r][i] = (wreg[r][i] >> 16) | (wreg[r][i + 1] << 16);
                wreg[r][15] = (wreg[r][15] >> 16) | ((u32)hb << 16);
                if (dec) {
                    float tacc = btv;
#pragma unroll
                    for (int i = 0; i < 16; ++i) {
                        u32 wv = wreg[r][i];
                        tacc += __uint_as_float(wv << 16) * wt[2 * i];
                        tacc += __uint_as_float(wv & 0xffff0000u) * wt[2 * i + 1];
                    }
                    myTileT[(quad * 4 + r) * 16 + l15] = f2bf(tacc);
                }
            }
            lds_drain();
            if (lane < 32) {
                short8 v = *(const short8*)(myTileH + srow * 16 + shalf * 8);
                st128_cc(h1g + (long)((u + 1) & 1) * GS +
                         (long)srow * SS + sg0 + shalf * 8, v);
                if (dec) {
                    short8 w = *(const short8*)(myTileT + srow * 16 + shalf * 8);
                    st128_cc(tsg + (long)(d & 1) * GS +
                             (long)srow * SS + sg0 + shalf * 8, w);
                    *(short8*)(temps + (long)d * (BB * SS) +
                               (long)(b0g + srow) * SS + sg0 + shalf * 8) = w;
                }
            }
            vm_drain();
            set_flag(f1 + myflag, u + 1);
        }
    }
}

// ---------------------------------------------------------------------------
// frames epilogue (parallel, MFMA): per batch b,
//   P[e][c] = temp(e)[b] . Ws[c];  frames[b][e][c] = x_last + cumsum(P + bs)
// ---------------------------------------------------------------------------
__global__ __launch_bounds__(256) void frames_kernel(
    const u16* __restrict__ temps, const float* __restrict__ x,
    const u16* __restrict__ wsb, const float* __restrict__ bs,
    float* __restrict__ outp)
{
    const int b = blockIdx.x, tid = threadIdx.x;
    const int wave = tid >> 6, lane = tid & 63;
    const int l15 = lane & 15, quad = lane >> 4;
    __shared__ float P[64][81];

    const int e0 = wave * 16;
    floatx4 acc[5];
#pragma unroll
    for (int ct = 0; ct < 5; ++ct) acc[ct] = (floatx4){0.f, 0.f, 0.f, 0.f};
    const u16* aBase =
        temps + (long)(e0 + l15) * (BB * SS) + (long)b * SS + quad * 8;
#pragma unroll
    for (int kc = 0; kc < 16; ++kc) {
        short8 a = *(const short8*)(aBase + kc * 32);
#pragma unroll
        for (int ct = 0; ct < 5; ++ct) {
            const u16* wp = wsb + (long)(ct * 16 + l15) * SS + quad * 8 + kc * 32;
            MFMA_BF16(a, wp, acc[ct]);
        }
    }
#pragma unroll
    for (int ct = 0; ct < 5; ++ct)
#pragma unroll
        for (int r = 0; r < 4; ++r)
            P[e0 + quad * 4 + r][ct * 16 + l15] = acc[ct][r];
    __syncthreads();

    const int c = tid;
    if (c < CC) {
        float cum = x[((long)b * TT + (TT - 1)) * CC + c];
        const float bsv = bs[c];
        for (int e = 0; e < TT; ++e) {
            cum += P[e][c] + bsv;
            outp[(long)b * TT * CC + (long)e * CC + c] = cum;
        }
    }
}

// ---------------------------------------------------------------------------
extern "C" void kernel_launch(void* const* d_in, const int* in_sizes, int n_in,
                              void* d_out, int out_size, void* d_ws, size_t ws_size,
                              hipStream_t stream)
{
    const float* x    = (const float*)d_in[0];
    const float* Wih0 = (const float*)d_in[1];
    const float* Whh0 = (const float*)d_in[2];
    const float* bih0 = (const float*)d_in[3];
    const float* bhh0 = (const float*)d_in[4];
    const float* Wih1 = (const float*)d_in[5];
    const float* Whh1 = (const float*)d_in[6];
    const float* bih1 = (const float*)d_in[7];
    const float* bhh1 = (const float*)d_in[8];
    const float* Wt   = (const float*)d_in[9];
    const float* bt   = (const float*)d_in[10];
    const float* Ws   = (const float*)d_in[11];
    const float* bs   = (const float*)d_in[12];
    float* outp = (float*)d_out;

    char* p = (char*)d_ws;
    auto alloc = [&](size_t bytes) -> char* {
        char* r = p; p += (bytes + 255) & ~(size_t)255; return r;
    };
    u16* h0buf = (u16*)alloc((size_t)NGRP * 4 * GS * 2);
    u16* h1buf = (u16*)alloc((size_t)NGRP * 2 * GS * 2);
    u16* tstage = (u16*)alloc((size_t)NGRP * 2 * GS * 2);
    u16* xbf = (u16*)alloc((size_t)BB * TT * CPAD * 2);
    u16* wi0 = (u16*)alloc((size_t)NGATE * CPAD * 2);
    u16* wh0 = (u16*)alloc((size_t)NGATE * SS * 2);
    u16* wi1 = (u16*)alloc((size_t)NGATE * SS * 2);
    u16* wh1 = (u16*)alloc((size_t)NGATE * SS * 2);
    u16* Mbf = (u16*)alloc((size_t)NGATE * SS * 2);
    u16* wsb = (u16*)alloc((size_t)80 * SS * 2);
    float* c0vec = (float*)alloc((size_t)NGATE * 4);
    float* gi0i  = (float*)alloc((size_t)BB * NGATE * 4);
    u16* temps = (u16*)alloc((size_t)TT * BB * SS * 2);
    int* gflags = (int*)alloc((size_t)NGRP * 1024 * 4);

    hipMemsetAsync(h0buf, 0, (size_t)NGRP * 4 * GS * 2, stream);
    hipMemsetAsync(h1buf, 0, (size_t)NGRP * 2 * GS * 2, stream);
    hipMemsetAsync(gflags, 0, (size_t)NGRP * 1024 * 4, stream);

    prep1_kernel<<<1024, 256, 0, stream>>>(x, Wih0, Whh0, Wih1, Whh1, Ws,
                                           xbf, wi0, wh0, wi1, wh1, wsb);
    prep2_kernel<<<1024, 256, 0, stream>>>(x, Wih0, Ws, bs, Mbf, c0vec, gi0i);

    persist_kernel<<<NGRP * GBLK, 256, 0, stream>>>(
        xbf, wi0, wh0, wi1, wh1, Mbf, bih0, bhh0, bih1, bhh1,
        c0vec, gi0i, Wt, bt, h0buf, h1buf, tstage, temps, gflags);

    frames_kernel<<<BB, 256, 0, stream>>>(temps, x, wsb, bs, outp);
}

// Round 11
// 4190.221 us; speedup vs baseline: 1.0079x; 1.0079x over previous
//
#include <hip/hip_runtime.h>
#include <stdint.h>

typedef unsigned short u16;
typedef uint32_t u32;
typedef __attribute__((ext_vector_type(8))) short short8;
typedef __attribute__((ext_vector_type(4))) float floatx4;

constexpr int BB = 128;     // batch
constexpr int TT = 64;      // time steps
constexpr int CC = 66;      // frame channels
constexpr int CPAD = 96;    // C padded to multiple of 32 (MFMA K-chunk)
constexpr int SS = 512;     // hidden
constexpr int NGATE = 1536; // 3*S
constexpr int NGRP = 8;     // batch groups (16 batches each)
constexpr int GBLK = 16;    // blocks per group (s-split by 32)
constexpr int GS = 16 * SS; // per-group state slab elements (16 x 512)

__device__ __forceinline__ u16 f2bf(float f) {
    u32 u = __float_as_uint(f);
    u32 r = (u + 0x7fffu + ((u >> 16) & 1u)) >> 16;
    return (u16)r;
}
__device__ __forceinline__ float bf2f(u16 h) {
    return __uint_as_float(((u32)h) << 16);
}
__device__ __forceinline__ float sigm(float x) { return 1.f / (1.f + __expf(-x)); }
__device__ __forceinline__ float tanh_f(float x) { return 1.f - 2.f / (1.f + __expf(2.f * x)); }

// ---- system-coherent (MALL) bulk-data primitives (proven rounds 3-6). ----
__device__ __forceinline__ void st128_cc(u16* p, short8 v) {
    asm volatile("global_store_dwordx4 %0, %1, off sc0 sc1"
                 :: "v"(p), "v"(v) : "memory");
}
__device__ __forceinline__ void ld128_cc(const u16* p, short8& d) {
    asm volatile("global_load_dwordx4 %0, %1, off sc0 sc1"
                 : "=v"(d) : "v"(p));
}
__device__ __forceinline__ void vm_drain() {
    asm volatile("s_waitcnt vmcnt(0)" ::: "memory");
}
__device__ __forceinline__ void lds_drain() {
    asm volatile("s_waitcnt lgkmcnt(0)" ::: "memory");
}

// ---- FLAGS: producer publishes via atomic RMW (fetch_max) -- executes at
// the coherence point, takes line ownership, INVALIDATES consumers' stale
// cached copies.  Consumers poll with plain agent-scope loads (cache-served,
// no fabric flood); their next poll after invalidation refetches fresh.
// This combines round 6's cheap polling with prompt visibility. ----
__device__ __forceinline__ void set_flag(int* f, int v) {
    if ((threadIdx.x & 63) == 0)
        __hip_atomic_fetch_max(f, v, __ATOMIC_RELAXED, __HIP_MEMORY_SCOPE_AGENT);
}
// ~64-cycle dependent-FMA backoff: keeps VALU issuing (DPM stays up),
// unlike s_sleep which advertises idleness.
__device__ __forceinline__ void spin_delay() {
    float a = 1.0f;
#pragma unroll
    for (int i = 0; i < 16; ++i) a = __builtin_fmaf(a, 1.0000001f, 0.0625f);
    asm volatile("" :: "v"(a));
}
// Combined wait with caching: lanes 0..31 poll the 32 f0 flags (64 B apart),
// lanes 32..63 poll f1.  Skips entirely once satisfied targets are cached.
__device__ __forceinline__ void wait2(const int* __restrict__ f0, int t0,
                                      const int* __restrict__ f1, int t1,
                                      int& c0, int& c1) {
    if (c0 >= t0 && c1 >= t1) return;
    const int lane = threadIdx.x & 63;
    const int* p = (lane < 32) ? (f0 + lane * 16) : (f1 + (lane - 32) * 16);
    const int tgt = (lane < 32) ? t0 : t1;
    for (;;) {
        int v = __hip_atomic_load(p, __ATOMIC_RELAXED, __HIP_MEMORY_SCOPE_AGENT);
        if (__all(v >= tgt)) break;
        spin_delay();
    }
    if (t0 > c0) c0 = t0;
    if (t1 > c1) c1 = t1;
    asm volatile("" ::: "memory");
}

// ---------------------------------------------------------------------------
// prep1: bf16 conversion of x (padded to 96), the 4 GRU weight matrices,
// and Ws -> bf16 [80][512] (c-padded) for the MFMA frames epilogue.
// ---------------------------------------------------------------------------
__global__ void prep1_kernel(const float* __restrict__ x,
                             const float* __restrict__ Wih0,
                             const float* __restrict__ Whh0,
                             const float* __restrict__ Wih1,
                             const float* __restrict__ Whh1,
                             const float* __restrict__ Ws,
                             u16* __restrict__ xbf, u16* __restrict__ wi0,
                             u16* __restrict__ wh0, u16* __restrict__ wi1,
                             u16* __restrict__ wh1, u16* __restrict__ wsb)
{
    const int N_xbf = BB * TT * CPAD;
    const int N_wi0 = NGATE * CPAD;
    const int N_whh = NGATE * SS;
    const int N_wsb = 80 * SS;
    const long total = (long)N_xbf + N_wi0 + 3L * N_whh + N_wsb;
    for (long i = (long)blockIdx.x * blockDim.x + threadIdx.x; i < total;
         i += (long)gridDim.x * blockDim.x) {
        long idx = i;
        if (idx < N_xbf) {
            int c = idx % CPAD; int bt = idx / CPAD;
            float v = (c < CC) ? x[(long)bt * CC + c] : 0.f;
            xbf[idx] = f2bf(v); continue;
        }
        idx -= N_xbf;
        if (idx < N_wi0) {
            int c = idx % CPAD; int n = idx / CPAD;
            float v = (c < CC) ? Wih0[(long)n * CC + c] : 0.f;
            wi0[idx] = f2bf(v); continue;
        }
        idx -= N_wi0;
        if (idx < N_whh) { wh0[idx] = f2bf(Whh0[idx]); continue; }
        idx -= N_whh;
        if (idx < N_whh) { wi1[idx] = f2bf(Wih1[idx]); continue; }
        idx -= N_whh;
        if (idx < N_whh) { wh1[idx] = f2bf(Whh1[idx]); continue; }
        idx -= N_whh;
        {
            int s = idx % SS; int c = idx / SS;
            wsb[idx] = (c < CC) ? f2bf(Ws[(long)c * SS + s]) : (u16)0;
        }
    }
}

// ---------------------------------------------------------------------------
// prep2: M = Wih0[:, :66] @ Ws (bf16); c0vec = Wih0 @ bs; gi0i = x_last@Wih0^T
// ---------------------------------------------------------------------------
__global__ void prep2_kernel(const float* __restrict__ x,
                             const float* __restrict__ Wih0,
                             const float* __restrict__ Ws,
                             const float* __restrict__ bs,
                             u16* __restrict__ Mbf, float* __restrict__ c0vec,
                             float* __restrict__ gi0i)
{
    const long NM = (long)NGATE * SS;
    const long NC = NGATE;
    const long NG = (long)BB * NGATE;
    const long total = NM + NC + NG;
    for (long i = (long)blockIdx.x * blockDim.x + threadIdx.x; i < total;
         i += (long)gridDim.x * blockDim.x) {
        long idx = i;
        if (idx < NM) {
            int s = idx % SS; int g = idx / SS;
            float acc = 0.f;
            for (int c = 0; c < CC; ++c)
                acc += Wih0[(long)g * CC + c] * Ws[(long)c * SS + s];
            Mbf[idx] = f2bf(acc); continue;
        }
        idx -= NM;
        if (idx < NC) {
            int g = idx;
            float acc = 0.f;
            for (int c = 0; c < CC; ++c) acc += Wih0[(long)g * CC + c] * bs[c];
            c0vec[g] = acc; continue;
        }
        idx -= NC;
        {
            int g = idx % NGATE; int b = idx / NGATE;
            float acc = 0.f;
            const float* xl = x + ((long)b * TT + (TT - 1)) * CC;
            for (int c = 0; c < CC; ++c) acc += xl[c] * Wih0[(long)g * CC + c];
            gi0i[idx] = acc;
        }
    }
}

// ---------------------------------------------------------------------------
// A-fragment direct load: 16 coherent dwordx4 per K=512 GEMM into registers.
// ---------------------------------------------------------------------------
__device__ __forceinline__ void load_afrags(const u16* __restrict__ st,
                                            int l15, int quad, short8* a) {
#pragma unroll
    for (int kc = 0; kc < 16; ++kc)
        ld128_cc(st + (long)l15 * SS + kc * 32 + quad * 8, a[kc]);
}

#define MFMA_BF16(a, wp, acc) \
    acc = __builtin_amdgcn_mfma_f32_16x16x32_bf16(a, *(const short8*)(wp), acc, 0, 0, 0)

__device__ __forceinline__ void mm3_reg(const short8* a,
                                        const u16* __restrict__ w0,
                                        const u16* __restrict__ w1,
                                        const u16* __restrict__ w2,
                                        floatx4& A0, floatx4& A1, floatx4& A2) {
#pragma unroll
    for (int kc = 0; kc < 16; ++kc) {
        const int k = kc << 5;
        MFMA_BF16(a[kc], w0 + k, A0);
        MFMA_BF16(a[kc], w1 + k, A1);
        MFMA_BF16(a[kc], w2 + k, A2);
    }
}

template <int K>
__device__ __forceinline__ void mm3_g(const u16* __restrict__ aP,
                                      const u16* __restrict__ w0,
                                      const u16* __restrict__ w1,
                                      const u16* __restrict__ w2,
                                      floatx4& A0, floatx4& A1, floatx4& A2) {
#pragma unroll
    for (int k = 0; k < K; k += 32) {
        short8 a = *(const short8*)(aP + k);
        MFMA_BF16(a, w0 + k, A0);
        MFMA_BF16(a, w1 + k, A1);
        MFMA_BF16(a, w2 + k, A2);
    }
}

// ---------------------------------------------------------------------------
// Persistent kernel, wave-decoupled dataflow.  grp = blk&7, rank = blk>>3.
// Waves 0,1 = layer-0 (s-sub 0/1), waves 2,3 = layer-1.  Data sc0sc1;
// flags: producer RMW (fetch_max) + consumer plain agent-load polling.
// State stores coalesced via per-wave LDS repack.
// ---------------------------------------------------------------------------
__global__ __launch_bounds__(256, 1) void persist_kernel(
    const u16* __restrict__ xbf,
    const u16* __restrict__ wi0, const u16* __restrict__ wh0,
    const u16* __restrict__ wi1, const u16* __restrict__ wh1,
    const u16* __restrict__ Mbf,
    const float* __restrict__ bih0, const float* __restrict__ bhh0,
    const float* __restrict__ bih1, const float* __restrict__ bhh1,
    const float* __restrict__ c0vec, const float* __restrict__ gi0i,
    const float* __restrict__ Wt, const float* __restrict__ bt,
    u16* __restrict__ h0buf,   // [NGRP][4][16][512]
    u16* __restrict__ h1buf,   // [NGRP][2][16][512]
    u16* __restrict__ tstage,  // [NGRP][2][16][512]
    u16* __restrict__ temps,   // [64][128][512] (cached; read by frames)
    int* __restrict__ gflags)  // [NGRP][1024]: f0 = 32x16 ints, f1 at +512
{
    __shared__ __align__(16) u16 tile[4][2][256];   // [wave][h/t][16x16]

    const int tid = threadIdx.x;
    const int wave = tid >> 6, lane = tid & 63;
    const int l15 = lane & 15, quad = lane >> 4;
    const int grp = blockIdx.x & 7, rank = blockIdx.x >> 3;
    const int b0g = grp * 16;
    const int wsub = wave & 1;
    const int sg0 = rank * 32 + wsub * 16;        // wave's 16-col s base
    const int sg = sg0 + l15;
    const bool l0w = wave < 2;

    u16* const h0g = h0buf + (long)grp * 4 * GS;
    u16* const h1g = h1buf + (long)grp * 2 * GS;
    u16* const tsg = tstage + (long)grp * 2 * GS;
    int* const f0 = gflags + grp * 1024;          // 32 flags, 64 B apart
    int* const f1 = f0 + 512;
    const int myflag = rank * 2 + wsub;

    // ---- per-thread constants & register state ----
    float bir, biz, bin, bhn;
    float c0r = 0.f, c0z = 0.f, c0n = 0.f;
    float hf[4] = {0.f, 0.f, 0.f, 0.f};
    float gi[12];
    float wt[32]; float btv = 0.f;
    u32 wreg[4][16];
#pragma unroll
    for (int r = 0; r < 4; ++r)
#pragma unroll
        for (int i = 0; i < 16; ++i) wreg[r][i] = 0u;

    if (l0w) {
        bir = bih0[sg] + bhh0[sg];
        biz = bih0[512 + sg] + bhh0[512 + sg];
        bin = bih0[1024 + sg];
        bhn = bhh0[1024 + sg];
        c0r = c0vec[sg]; c0z = c0vec[512 + sg]; c0n = c0vec[1024 + sg];
#pragma unroll
        for (int g3 = 0; g3 < 3; ++g3)
#pragma unroll
            for (int r = 0; r < 4; ++r)
                gi[g3 * 4 + r] =
                    gi0i[(long)(b0g + quad * 4 + r) * NGATE + g3 * 512 + sg];
    } else {
        bir = bih1[sg] + bhh1[sg];
        biz = bih1[512 + sg] + bhh1[512 + sg];
        bin = bih1[1024 + sg];
        bhn = bhh1[1024 + sg];
#pragma unroll
        for (int j = 0; j < 32; ++j) wt[j] = Wt[j];
        btv = bt[0];
    }

    const u16 *wiR, *wiZ, *wiN, *whR, *whZ, *whN, *mR, *mZ, *mN;
    if (l0w) {
        wiR = wi0 + (long)sg * CPAD + quad * 8;
        wiZ = wi0 + (long)(512 + sg) * CPAD + quad * 8;
        wiN = wi0 + (long)(1024 + sg) * CPAD + quad * 8;
        whR = wh0 + (long)sg * SS + quad * 8;
        whZ = wh0 + (long)(512 + sg) * SS + quad * 8;
        whN = wh0 + (long)(1024 + sg) * SS + quad * 8;
        mR = Mbf + (long)sg * SS + quad * 8;
        mZ = Mbf + (long)(512 + sg) * SS + quad * 8;
        mN = Mbf + (long)(1024 + sg) * SS + quad * 8;
    } else {
        wiR = wi1 + (long)sg * SS + quad * 8;
        wiZ = wi1 + (long)(512 + sg) * SS + quad * 8;
        wiN = wi1 + (long)(1024 + sg) * SS + quad * 8;
        whR = wh1 + (long)sg * SS + quad * 8;
        whZ = wh1 + (long)(512 + sg) * SS + quad * 8;
        whN = wh1 + (long)(1024 + sg) * SS + quad * 8;
        mR = mZ = mN = nullptr;
    }

    // coalesced-store lane roles (lanes 0..31): row, half
    const int srow = lane >> 1, shalf = lane & 1;
    u16* const myTileH = &tile[wave][0][0];
    u16* const myTileT = &tile[wave][1][0];

    short8 fa[16], fb[16];
    int c0 = 0, c1 = 0;   // cached lower bounds of min(f0), min(f1)
    if (l0w) {
        // ========== layer-0 wave: encoder t=0..62 ==========
#pragma clang loop unroll(disable)
        for (int t = 0; t < 63; ++t) {
            floatx4 aR = {0,0,0,0}, aZ = aR, aNI = aR, aNH = aR;
            const u16* aP =
                xbf + ((long)(b0g + l15) * TT + t) * CPAD + quad * 8;
            mm3_g<CPAD>(aP, wiR, wiZ, wiN, aR, aZ, aNI);
            wait2(f0, t, f1, t - 3, c0, c1);   // data ready + depth-4 guard
            load_afrags(h0g + (long)(t & 3) * GS, l15, quad, fa);
            vm_drain();
            mm3_reg(fa, whR, whZ, whN, aR, aZ, aNH);
#pragma unroll
            for (int r = 0; r < 4; ++r) {
                float rr = sigm(aR[r] + bir);
                float zz = sigm(aZ[r] + biz);
                float nn = tanh_f(aNI[r] + bin + rr * (aNH[r] + bhn));
                float hv = (1.f - zz) * nn + zz * hf[r];
                hf[r] = hv;
                myTileH[(quad * 4 + r) * 16 + l15] = f2bf(hv);
            }
            lds_drain();
            if (lane < 32) {
                short8 v = *(const short8*)(myTileH + srow * 16 + shalf * 8);
                st128_cc(h0g + (long)((t + 1) & 3) * GS +
                         (long)srow * SS + sg0 + shalf * 8, v);
            }
            vm_drain();
            set_flag(f0 + myflag * 16, t + 1);
        }
        // ========== layer-0 wave: decoder d=0..63 ==========
#pragma clang loop unroll(disable)
        for (int d = 0; d < 64; ++d) {
            const int t = 63 + d;
            wait2(f0, t, f1, (d > 0) ? t : 60, c0, c1);
            load_afrags(h0g + (long)(t & 3) * GS, l15, quad, fa);
            if (d > 0)
                load_afrags(tsg + (long)((d - 1) & 1) * GS, l15, quad, fb);
            vm_drain();
            if (d > 0) {   // gi(d) = gi(d-1) + M @ temp(d-1) + c0
                floatx4 tR = {0,0,0,0}, tZ = tR, tN = tR;
                mm3_reg(fb, mR, mZ, mN, tR, tZ, tN);
#pragma unroll
                for (int r = 0; r < 4; ++r) {
                    gi[r] += tR[r] + c0r;
                    gi[4 + r] += tZ[r] + c0z;
                    gi[8 + r] += tN[r] + c0n;
                }
            }
            floatx4 hR = {0,0,0,0}, hZ = hR, hN4 = hR;
            mm3_reg(fa, whR, whZ, whN, hR, hZ, hN4);
#pragma unroll
            for (int r = 0; r < 4; ++r) {
                float rr = sigm(gi[r] + hR[r] + bir);
                float zz = sigm(gi[4 + r] + hZ[r] + biz);
                float nn = tanh_f(gi[8 + r] + bin + rr * (hN4[r] + bhn));
                float hv = (1.f - zz) * nn + zz * hf[r];
                hf[r] = hv;
                myTileH[(quad * 4 + r) * 16 + l15] = f2bf(hv);
            }
            lds_drain();
            if (lane < 32) {
                short8 v = *(const short8*)(myTileH + srow * 16 + shalf * 8);
                st128_cc(h0g + (long)((t + 1) & 3) * GS +
                         (long)srow * SS + sg0 + shalf * 8, v);
            }
            vm_drain();
            set_flag(f0 + myflag * 16, t + 1);
        }
    } else {
        // ========== layer-1 wave: u = 0..126 ==========
#pragma clang loop unroll(disable)
        for (int u = 0; u < 127; ++u) {
            const bool dec = (u >= 63);
            const int d = u - 63;
            wait2(f0, u + 1, f1, u, c0, c1);
            load_afrags(h0g + (long)((u + 1) & 3) * GS, l15, quad, fa);
            load_afrags(h1g + (long)(u & 1) * GS, l15, quad, fb);
            vm_drain();
            floatx4 aR = {0,0,0,0}, aZ = aR, aNI = aR, aNH = aR;
            mm3_reg(fa, wiR, wiZ, wiN, aR, aZ, aNI);
            mm3_reg(fb, whR, whZ, whN, aR, aZ, aNH);
#pragma unroll
            for (int r = 0; r < 4; ++r) {
                float rr = sigm(aR[r] + bir);
                float zz = sigm(aZ[r] + biz);
                float nn = tanh_f(aNI[r] + bin + rr * (aNH[r] + bhn));
                float hv = (1.f - zz) * nn + zz * hf[r];
                hf[r] = hv;
                u16 hb = f2bf(hv);
                myTileH[(quad * 4 + r) * 16 + l15] = hb;
#pragma unroll
                for (int i = 0; i < 15; ++i)
                    wreg[r][i] = (wreg[r][i] >> 16) | (wreg[r][i + 1] << 16);
                wreg[r][15] = (wreg[r][15] >> 16) | ((u32)hb << 16);
                if (dec) {
                    float tacc = btv;
#pragma unroll
                    for (int i = 0; i < 16; ++i) {
                        u32 wv = wreg[r][i];
                        tacc += __uint_as_float(wv << 16) * wt[2 * i];
                        tacc += __uint_as_float(wv & 0xffff0000u) * wt[2 * i + 1];
                    }
                    myTileT[(quad * 4 + r) * 16 + l15] = f2bf(tacc);
                }
            }
            lds_drain();
            if (lane < 32) {
                short8 v = *(const short8*)(myTileH + srow * 16 + shalf * 8);
                st128_cc(h1g + (long)((u + 1) & 1) * GS +
                         (long)srow * SS + sg0 + shalf * 8, v);
                if (dec) {
                    short8 w = *(const short8*)(myTileT + srow * 16 + shalf * 8);
                    st128_cc(tsg + (long)(d & 1) * GS +
                             (long)srow * SS + sg0 + shalf * 8, w);
                    *(short8*)(temps + (long)d * (BB * SS) +
                               (long)(b0g + srow) * SS + sg0 + shalf * 8) = w;
                }
            }
            vm_drain();
            set_flag(f1 + myflag * 16, u + 1);
        }
    }
}

// ---------------------------------------------------------------------------
// frames epilogue (parallel, MFMA): per batch b,
//   P[e][c] = temp(e)[b] . Ws[c];  frames[b][e][c] = x_last + cumsum(P + bs)
// ---------------------------------------------------------------------------
__global__ __launch_bounds__(256) void frames_kernel(
    const u16* __restrict__ temps, const float* __restrict__ x,
    const u16* __restrict__ wsb, const float* __restrict__ bs,
    float* __restrict__ outp)
{
    const int b = blockIdx.x, tid = threadIdx.x;
    const int wave = tid >> 6, lane = tid & 63;
    const int l15 = lane & 15, quad = lane >> 4;
    __shared__ float P[64][81];

    const int e0 = wave * 16;
    floatx4 acc[5];
#pragma unroll
    for (int ct = 0; ct < 5; ++ct) acc[ct] = (floatx4){0.f, 0.f, 0.f, 0.f};
    const u16* aBase =
        temps + (long)(e0 + l15) * (BB * SS) + (long)b * SS + quad * 8;
#pragma unroll
    for (int kc = 0; kc < 16; ++kc) {
        short8 a = *(const short8*)(aBase + kc * 32);
#pragma unroll
        for (int ct = 0; ct < 5; ++ct) {
            const u16* wp = wsb + (long)(ct * 16 + l15) * SS + quad * 8 + kc * 32;
            MFMA_BF16(a, wp, acc[ct]);
        }
    }
#pragma unroll
    for (int ct = 0; ct < 5; ++ct)
#pragma unroll
        for (int r = 0; r < 4; ++r)
            P[e0 + quad * 4 + r][ct * 16 + l15] = acc[ct][r];
    __syncthreads();

    const int c = tid;
    if (c < CC) {
        float cum = x[((long)b * TT + (TT - 1)) * CC + c];
        const float bsv = bs[c];
        for (int e = 0; e < TT; ++e) {
            cum += P[e][c] + bsv;
            outp[(long)b * TT * CC + (long)e * CC + c] = cum;
        }
    }
}

// ---------------------------------------------------------------------------
extern "C" void kernel_launch(void* const* d_in, const int* in_sizes, int n_in,
                              void* d_out, int out_size, void* d_ws, size_t ws_size,
                              hipStream_t stream)
{
    const float* x    = (const float*)d_in[0];
    const float* Wih0 = (const float*)d_in[1];
    const float* Whh0 = (const float*)d_in[2];
    const float* bih0 = (const float*)d_in[3];
    const float* bhh0 = (const float*)d_in[4];
    const float* Wih1 = (const float*)d_in[5];
    const float* Whh1 = (const float*)d_in[6];
    const float* bih1 = (const float*)d_in[7];
    const float* bhh1 = (const float*)d_in[8];
    const float* Wt   = (const float*)d_in[9];
    const float* bt   = (const float*)d_in[10];
    const float* Ws   = (const float*)d_in[11];
    const float* bs   = (const float*)d_in[12];
    float* outp = (float*)d_out;

    char* p = (char*)d_ws;
    auto alloc = [&](size_t bytes) -> char* {
        char* r = p; p += (bytes + 255) & ~(size_t)255; return r;
    };
    u16* h0buf = (u16*)alloc((size_t)NGRP * 4 * GS * 2);
    u16* h1buf = (u16*)alloc((size_t)NGRP * 2 * GS * 2);
    u16* tstage = (u16*)alloc((size_t)NGRP * 2 * GS * 2);
    u16* xbf = (u16*)alloc((size_t)BB * TT * CPAD * 2);
    u16* wi0 = (u16*)alloc((size_t)NGATE * CPAD * 2);
    u16* wh0 = (u16*)alloc((size_t)NGATE * SS * 2);
    u16* wi1 = (u16*)alloc((size_t)NGATE * SS * 2);
    u16* wh1 = (u16*)alloc((size_t)NGATE * SS * 2);
    u16* Mbf = (u16*)alloc((size_t)NGATE * SS * 2);
    u16* wsb = (u16*)alloc((size_t)80 * SS * 2);
    float* c0vec = (float*)alloc((size_t)NGATE * 4);
    float* gi0i  = (float*)alloc((size_t)BB * NGATE * 4);
    u16* temps = (u16*)alloc((size_t)TT * BB * SS * 2);
    int* gflags = (int*)alloc((size_t)NGRP * 1024 * 4);

    hipMemsetAsync(h0buf, 0, (size_t)NGRP * 4 * GS * 2, stream);
    hipMemsetAsync(h1buf, 0, (size_t)NGRP * 2 * GS * 2, stream);
    hipMemsetAsync(gflags, 0, (size_t)NGRP * 1024 * 4, stream);

    prep1_kernel<<<1024, 256, 0, stream>>>(x, Wih0, Whh0, Wih1, Whh1, Ws,
                                           xbf, wi0, wh0, wi1, wh1, wsb);
    prep2_kernel<<<1024, 256, 0, stream>>>(x, Wih0, Ws, bs, Mbf, c0vec, gi0i);

    persist_kernel<<<NGRP * GBLK, 256, 0, stream>>>(
        xbf, wi0, wh0, wi1, wh1, Mbf, bih0, bhh0, bih1, bhh1,
        c0vec, gi0i, Wt, bt, h0buf, h1buf, tstage, temps, gflags);

    frames_kernel<<<BB, 256, 0, stream>>>(temps, x, wsb, bs, outp);
}

// Round 12
// 3597.667 us; speedup vs baseline: 1.1740x; 1.1647x over previous
//
#include <hip/hip_runtime.h>
#include <stdint.h>

typedef unsigned short u16;
typedef uint32_t u32;
typedef __attribute__((ext_vector_type(8))) short short8;
typedef __attribute__((ext_vector_type(4))) float floatx4;

constexpr int BB = 128;     // batch
constexpr int TT = 64;      // time steps
constexpr int CC = 66;      // frame channels
constexpr int CPAD = 96;    // C padded to multiple of 32 (MFMA K-chunk)
constexpr int SS = 512;     // hidden
constexpr int NGATE = 1536; // 3*S
constexpr int NGRP = 8;     // batch groups (16 batches each)
constexpr int GBLK = 16;    // blocks per group (s-split by 32)
constexpr int GS = 16 * SS; // per-group state slab elements (16 x 512)

__device__ __forceinline__ u16 f2bf(float f) {
    u32 u = __float_as_uint(f);
    u32 r = (u + 0x7fffu + ((u >> 16) & 1u)) >> 16;
    return (u16)r;
}
__device__ __forceinline__ float bf2f(u16 h) {
    return __uint_as_float(((u32)h) << 16);
}
__device__ __forceinline__ float sigm(float x) { return 1.f / (1.f + __expf(-x)); }
__device__ __forceinline__ float tanh_f(float x) { return 1.f - 2.f / (1.f + __expf(2.f * x)); }

// ---- system-coherent (MALL) bulk-data primitives.  NOTE: these bypass L2
// (invisible to FETCH_SIZE); weights/x use normal cached loads and MUST stay
// L2-resident -- which requires the rank-spread block mapping below. ----
__device__ __forceinline__ void st128_cc(u16* p, short8 v) {
    asm volatile("global_store_dwordx4 %0, %1, off sc0 sc1"
                 :: "v"(p), "v"(v) : "memory");
}
__device__ __forceinline__ void ld128_cc(const u16* p, short8& d) {
    asm volatile("global_load_dwordx4 %0, %1, off sc0 sc1"
                 : "=v"(d) : "v"(p));
}
__device__ __forceinline__ void vm_drain() {
    asm volatile("s_waitcnt vmcnt(0)" ::: "memory");
}
__device__ __forceinline__ void lds_drain() {
    asm volatile("s_waitcnt lgkmcnt(0)" ::: "memory");
}

// ---- FLAGS: producer publishes via atomic RMW (fetch_max -- executes at the
// coherence point, takes line ownership, invalidating consumers' stale cached
// copies); consumers poll with plain agent-scope loads (cache-served). ----
__device__ __forceinline__ void set_flag(int* f, int v) {
    if ((threadIdx.x & 63) == 0)
        __hip_atomic_fetch_max(f, v, __ATOMIC_RELAXED, __HIP_MEMORY_SCOPE_AGENT);
}
// ~64-cycle dependent-FMA backoff (keeps VALU busy; DPM stays up).
__device__ __forceinline__ void spin_delay() {
    float a = 1.0f;
#pragma unroll
    for (int i = 0; i < 16; ++i) a = __builtin_fmaf(a, 1.0000001f, 0.0625f);
    asm volatile("" :: "v"(a));
}
// Combined wait with caching: lanes 0..31 poll the 32 f0 flags (64 B apart),
// lanes 32..63 poll f1.  Skips entirely once satisfied targets are cached.
__device__ __forceinline__ void wait2(const int* __restrict__ f0, int t0,
                                      const int* __restrict__ f1, int t1,
                                      int& c0, int& c1) {
    if (c0 >= t0 && c1 >= t1) return;
    const int lane = threadIdx.x & 63;
    const int* p = (lane < 32) ? (f0 + lane * 16) : (f1 + (lane - 32) * 16);
    const int tgt = (lane < 32) ? t0 : t1;
    for (;;) {
        int v = __hip_atomic_load(p, __ATOMIC_RELAXED, __HIP_MEMORY_SCOPE_AGENT);
        if (__all(v >= tgt)) break;
        spin_delay();
    }
    if (t0 > c0) c0 = t0;
    if (t1 > c1) c1 = t1;
    asm volatile("" ::: "memory");
}

// ---------------------------------------------------------------------------
// prep1: bf16 conversion of x (padded to 96), the 4 GRU weight matrices,
// and Ws -> bf16 [80][512] (c-padded) for the MFMA frames epilogue.
// ---------------------------------------------------------------------------
__global__ void prep1_kernel(const float* __restrict__ x,
                             const float* __restrict__ Wih0,
                             const float* __restrict__ Whh0,
                             const float* __restrict__ Wih1,
                             const float* __restrict__ Whh1,
                             const float* __restrict__ Ws,
                             u16* __restrict__ xbf, u16* __restrict__ wi0,
                             u16* __restrict__ wh0, u16* __restrict__ wi1,
                             u16* __restrict__ wh1, u16* __restrict__ wsb)
{
    const int N_xbf = BB * TT * CPAD;
    const int N_wi0 = NGATE * CPAD;
    const int N_whh = NGATE * SS;
    const int N_wsb = 80 * SS;
    const long total = (long)N_xbf + N_wi0 + 3L * N_whh + N_wsb;
    for (long i = (long)blockIdx.x * blockDim.x + threadIdx.x; i < total;
         i += (long)gridDim.x * blockDim.x) {
        long idx = i;
        if (idx < N_xbf) {
            int c = idx % CPAD; int bt = idx / CPAD;
            float v = (c < CC) ? x[(long)bt * CC + c] : 0.f;
            xbf[idx] = f2bf(v); continue;
        }
        idx -= N_xbf;
        if (idx < N_wi0) {
            int c = idx % CPAD; int n = idx / CPAD;
            float v = (c < CC) ? Wih0[(long)n * CC + c] : 0.f;
            wi0[idx] = f2bf(v); continue;
        }
        idx -= N_wi0;
        if (idx < N_whh) { wh0[idx] = f2bf(Whh0[idx]); continue; }
        idx -= N_whh;
        if (idx < N_whh) { wi1[idx] = f2bf(Wih1[idx]); continue; }
        idx -= N_whh;
        if (idx < N_whh) { wh1[idx] = f2bf(Whh1[idx]); continue; }
        idx -= N_whh;
        {
            int s = idx % SS; int c = idx / SS;
            wsb[idx] = (c < CC) ? f2bf(Ws[(long)c * SS + s]) : (u16)0;
        }
    }
}

// ---------------------------------------------------------------------------
// prep2: M = Wih0[:, :66] @ Ws (bf16); c0vec = Wih0 @ bs; gi0i = x_last@Wih0^T
// ---------------------------------------------------------------------------
__global__ void prep2_kernel(const float* __restrict__ x,
                             const float* __restrict__ Wih0,
                             const float* __restrict__ Ws,
                             const float* __restrict__ bs,
                             u16* __restrict__ Mbf, float* __restrict__ c0vec,
                             float* __restrict__ gi0i)
{
    const long NM = (long)NGATE * SS;
    const long NC = NGATE;
    const long NG = (long)BB * NGATE;
    const long total = NM + NC + NG;
    for (long i = (long)blockIdx.x * blockDim.x + threadIdx.x; i < total;
         i += (long)gridDim.x * blockDim.x) {
        long idx = i;
        if (idx < NM) {
            int s = idx % SS; int g = idx / SS;
            float acc = 0.f;
            for (int c = 0; c < CC; ++c)
                acc += Wih0[(long)g * CC + c] * Ws[(long)c * SS + s];
            Mbf[idx] = f2bf(acc); continue;
        }
        idx -= NM;
        if (idx < NC) {
            int g = idx;
            float acc = 0.f;
            for (int c = 0; c < CC; ++c) acc += Wih0[(long)g * CC + c] * bs[c];
            c0vec[g] = acc; continue;
        }
        idx -= NC;
        {
            int g = idx % NGATE; int b = idx / NGATE;
            float acc = 0.f;
            const float* xl = x + ((long)b * TT + (TT - 1)) * CC;
            for (int c = 0; c < CC; ++c) acc += xl[c] * Wih0[(long)g * CC + c];
            gi0i[idx] = acc;
        }
    }
}

// ---------------------------------------------------------------------------
// A-fragment direct load: 16 coherent dwordx4 per K=512 GEMM into registers.
// ---------------------------------------------------------------------------
__device__ __forceinline__ void load_afrags(const u16* __restrict__ st,
                                            int l15, int quad, short8* a) {
#pragma unroll
    for (int kc = 0; kc < 16; ++kc)
        ld128_cc(st + (long)l15 * SS + kc * 32 + quad * 8, a[kc]);
}

#define MFMA_BF16(a, wp, acc) \
    acc = __builtin_amdgcn_mfma_f32_16x16x32_bf16(a, *(const short8*)(wp), acc, 0, 0, 0)

__device__ __forceinline__ void mm3_reg(const short8* a,
                                        const u16* __restrict__ w0,
                                        const u16* __restrict__ w1,
                                        const u16* __restrict__ w2,
                                        floatx4& A0, floatx4& A1, floatx4& A2) {
#pragma unroll
    for (int kc = 0; kc < 16; ++kc) {
        const int k = kc << 5;
        MFMA_BF16(a[kc], w0 + k, A0);
        MFMA_BF16(a[kc], w1 + k, A1);
        MFMA_BF16(a[kc], w2 + k, A2);
    }
}

template <int K>
__device__ __forceinline__ void mm3_g(const u16* __restrict__ aP,
                                      const u16* __restrict__ w0,
                                      const u16* __restrict__ w1,
                                      const u16* __restrict__ w2,
                                      floatx4& A0, floatx4& A1, floatx4& A2) {
#pragma unroll
    for (int k = 0; k < K; k += 32) {
        short8 a = *(const short8*)(aP + k);
        MFMA_BF16(a, w0 + k, A0);
        MFMA_BF16(a, w1 + k, A1);
        MFMA_BF16(a, w2 + k, A2);
    }
}

// ---------------------------------------------------------------------------
// Persistent kernel, wave-decoupled dataflow.
// MAPPING (critical, round-12 fix): grp = blk>>4, rank = blk&15.  Under
// round-robin dispatch each XCD hosts ranks {x, x+8} of every group ->
// per-XCD weight working set = 64/512 of rows (~0.8 MB) -> L2-resident.
// The round-7..11 mapping (grp=blk&7) put ALL 16 ranks (full 6.3 MB of
// weights) on each XCD -> L2 thrash -> the 2.65 GB FETCH / ~4 ms regression.
// Waves 0,1 = layer-0 (s-sub 0/1), waves 2,3 = layer-1.  Data sc0sc1;
// flags RMW-publish + cached agent polls; stores coalesced via LDS repack.
// ---------------------------------------------------------------------------
__global__ __launch_bounds__(256, 1) void persist_kernel(
    const u16* __restrict__ xbf,
    const u16* __restrict__ wi0, const u16* __restrict__ wh0,
    const u16* __restrict__ wi1, const u16* __restrict__ wh1,
    const u16* __restrict__ Mbf,
    const float* __restrict__ bih0, const float* __restrict__ bhh0,
    const float* __restrict__ bih1, const float* __restrict__ bhh1,
    const float* __restrict__ c0vec, const float* __restrict__ gi0i,
    const float* __restrict__ Wt, const float* __restrict__ bt,
    u16* __restrict__ h0buf,   // [NGRP][4][16][512]
    u16* __restrict__ h1buf,   // [NGRP][2][16][512]
    u16* __restrict__ tstage,  // [NGRP][2][16][512]
    u16* __restrict__ temps,   // [64][128][512] (cached; read by frames)
    int* __restrict__ gflags)  // [NGRP][1024]: f0 = 32x16 ints, f1 at +512
{
    __shared__ __align__(16) u16 tile[4][2][256];   // [wave][h/t][16x16]

    const int tid = threadIdx.x;
    const int wave = tid >> 6, lane = tid & 63;
    const int l15 = lane & 15, quad = lane >> 4;
    const int grp = blockIdx.x >> 4, rank = blockIdx.x & 15;   // round-6 map
    const int b0g = grp * 16;
    const int wsub = wave & 1;
    const int sg0 = rank * 32 + wsub * 16;        // wave's 16-col s base
    const int sg = sg0 + l15;
    const bool l0w = wave < 2;

    u16* const h0g = h0buf + (long)grp * 4 * GS;
    u16* const h1g = h1buf + (long)grp * 2 * GS;
    u16* const tsg = tstage + (long)grp * 2 * GS;
    int* const f0 = gflags + grp * 1024;          // 32 flags, 64 B apart
    int* const f1 = f0 + 512;
    const int myflag = rank * 2 + wsub;

    // ---- per-thread constants & register state ----
    float bir, biz, bin, bhn;
    float c0r = 0.f, c0z = 0.f, c0n = 0.f;
    float hf[4] = {0.f, 0.f, 0.f, 0.f};
    float gi[12];
    float wt[32]; float btv = 0.f;
    u32 wreg[4][16];
#pragma unroll
    for (int r = 0; r < 4; ++r)
#pragma unroll
        for (int i = 0; i < 16; ++i) wreg[r][i] = 0u;

    if (l0w) {
        bir = bih0[sg] + bhh0[sg];
        biz = bih0[512 + sg] + bhh0[512 + sg];
        bin = bih0[1024 + sg];
        bhn = bhh0[1024 + sg];
        c0r = c0vec[sg]; c0z = c0vec[512 + sg]; c0n = c0vec[1024 + sg];
#pragma unroll
        for (int g3 = 0; g3 < 3; ++g3)
#pragma unroll
            for (int r = 0; r < 4; ++r)
                gi[g3 * 4 + r] =
                    gi0i[(long)(b0g + quad * 4 + r) * NGATE + g3 * 512 + sg];
    } else {
        bir = bih1[sg] + bhh1[sg];
        biz = bih1[512 + sg] + bhh1[512 + sg];
        bin = bih1[1024 + sg];
        bhn = bhh1[1024 + sg];
#pragma unroll
        for (int j = 0; j < 32; ++j) wt[j] = Wt[j];
        btv = bt[0];
    }

    const u16 *wiR, *wiZ, *wiN, *whR, *whZ, *whN, *mR, *mZ, *mN;
    if (l0w) {
        wiR = wi0 + (long)sg * CPAD + quad * 8;
        wiZ = wi0 + (long)(512 + sg) * CPAD + quad * 8;
        wiN = wi0 + (long)(1024 + sg) * CPAD + quad * 8;
        whR = wh0 + (long)sg * SS + quad * 8;
        whZ = wh0 + (long)(512 + sg) * SS + quad * 8;
        whN = wh0 + (long)(1024 + sg) * SS + quad * 8;
        mR = Mbf + (long)sg * SS + quad * 8;
        mZ = Mbf + (long)(512 + sg) * SS + quad * 8;
        mN = Mbf + (long)(1024 + sg) * SS + quad * 8;
    } else {
        wiR = wi1 + (long)sg * SS + quad * 8;
        wiZ = wi1 + (long)(512 + sg) * SS + quad * 8;
        wiN = wi1 + (long)(1024 + sg) * SS + quad * 8;
        whR = wh1 + (long)sg * SS + quad * 8;
        whZ = wh1 + (long)(512 + sg) * SS + quad * 8;
        whN = wh1 + (long)(1024 + sg) * SS + quad * 8;
        mR = mZ = mN = nullptr;
    }

    // coalesced-store lane roles (lanes 0..31): row, half
    const int srow = lane >> 1, shalf = lane & 1;
    u16* const myTileH = &tile[wave][0][0];
    u16* const myTileT = &tile[wave][1][0];

    short8 fa[16], fb[16];
    int c0 = 0, c1 = 0;   // cached lower bounds of min(f0), min(f1)
    if (l0w) {
        // ========== layer-0 wave: encoder t=0..62 ==========
#pragma clang loop unroll(disable)
        for (int t = 0; t < 63; ++t) {
            floatx4 aR = {0,0,0,0}, aZ = aR, aNI = aR, aNH = aR;
            const u16* aP =
                xbf + ((long)(b0g + l15) * TT + t) * CPAD + quad * 8;
            mm3_g<CPAD>(aP, wiR, wiZ, wiN, aR, aZ, aNI);
            wait2(f0, t, f1, t - 3, c0, c1);   // data ready + depth-4 guard
            load_afrags(h0g + (long)(t & 3) * GS, l15, quad, fa);
            vm_drain();
            mm3_reg(fa, whR, whZ, whN, aR, aZ, aNH);
#pragma unroll
            for (int r = 0; r < 4; ++r) {
                float rr = sigm(aR[r] + bir);
                float zz = sigm(aZ[r] + biz);
                float nn = tanh_f(aNI[r] + bin + rr * (aNH[r] + bhn));
                float hv = (1.f - zz) * nn + zz * hf[r];
                hf[r] = hv;
                myTileH[(quad * 4 + r) * 16 + l15] = f2bf(hv);
            }
            lds_drain();
            if (lane < 32) {
                short8 v = *(const short8*)(myTileH + srow * 16 + shalf * 8);
                st128_cc(h0g + (long)((t + 1) & 3) * GS +
                         (long)srow * SS + sg0 + shalf * 8, v);
            }
            vm_drain();
            set_flag(f0 + myflag * 16, t + 1);
        }
        // ========== layer-0 wave: decoder d=0..63 ==========
#pragma clang loop unroll(disable)
        for (int d = 0; d < 64; ++d) {
            const int t = 63 + d;
            wait2(f0, t, f1, (d > 0) ? t : 60, c0, c1);
            load_afrags(h0g + (long)(t & 3) * GS, l15, quad, fa);
            if (d > 0)
                load_afrags(tsg + (long)((d - 1) & 1) * GS, l15, quad, fb);
            vm_drain();
            if (d > 0) {   // gi(d) = gi(d-1) + M @ temp(d-1) + c0
                floatx4 tR = {0,0,0,0}, tZ = tR, tN = tR;
                mm3_reg(fb, mR, mZ, mN, tR, tZ, tN);
#pragma unroll
                for (int r = 0; r < 4; ++r) {
                    gi[r] += tR[r] + c0r;
                    gi[4 + r] += tZ[r] + c0z;
                    gi[8 + r] += tN[r] + c0n;
                }
            }
            floatx4 hR = {0,0,0,0}, hZ = hR, hN4 = hR;
            mm3_reg(fa, whR, whZ, whN, hR, hZ, hN4);
#pragma unroll
            for (int r = 0; r < 4; ++r) {
                float rr = sigm(gi[r] + hR[r] + bir);
                float zz = sigm(gi[4 + r] + hZ[r] + biz);
                float nn = tanh_f(gi[8 + r] + bin + rr * (hN4[r] + bhn));
                float hv = (1.f - zz) * nn + zz * hf[r];
                hf[r] = hv;
                myTileH[(quad * 4 + r) * 16 + l15] = f2bf(hv);
            }
            lds_drain();
            if (lane < 32) {
                short8 v = *(const short8*)(myTileH + srow * 16 + shalf * 8);
                st128_cc(h0g + (long)((t + 1) & 3) * GS +
                         (long)srow * SS + sg0 + shalf * 8, v);
            }
            vm_drain();
            set_flag(f0 + myflag * 16, t + 1);
        }
    } else {
        // ========== layer-1 wave: u = 0..126 ==========
#pragma clang loop unroll(disable)
        for (int u = 0; u < 127; ++u) {
            const bool dec = (u >= 63);
            const int d = u - 63;
            wait2(f0, u + 1, f1, u, c0, c1);
            load_afrags(h0g + (long)((u + 1) & 3) * GS, l15, quad, fa);
            load_afrags(h1g + (long)(u & 1) * GS, l15, quad, fb);
            vm_drain();
            floatx4 aR = {0,0,0,0}, aZ = aR, aNI = aR, aNH = aR;
            mm3_reg(fa, wiR, wiZ, wiN, aR, aZ, aNI);
            mm3_reg(fb, whR, whZ, whN, aR, aZ, aNH);
#pragma unroll
            for (int r = 0; r < 4; ++r) {
                float rr = sigm(aR[r] + bir);
                float zz = sigm(aZ[r] + biz);
                float nn = tanh_f(aNI[r] + bin + rr * (aNH[r] + bhn));
                float hv = (1.f - zz) * nn + zz * hf[r];
                hf[r] = hv;
                u16 hb = f2bf(hv);
                myTileH[(quad * 4 + r) * 16 + l15] = hb;
#pragma unroll
                for (int i = 0; i < 15; ++i)
                    wreg[r][i] = (wreg[r][i] >> 16) | (wreg[r][i + 1] << 16);
                wreg[r][15] = (wreg[r][15] >> 16) | ((u32)hb << 16);
                if (dec) {
                    float tacc = btv;
#pragma unroll
                    for (int i = 0; i < 16; ++i) {
                        u32 wv = wreg[r][i];
                        tacc += __uint_as_float(wv << 16) * wt[2 * i];
                        tacc += __uint_as_float(wv & 0xffff0000u) * wt[2 * i + 1];
                    }
                    myTileT[(quad * 4 + r) * 16 + l15] = f2bf(tacc);
                }
            }
            lds_drain();
            if (lane < 32) {
                short8 v = *(const short8*)(myTileH + srow * 16 + shalf * 8);
                st128_cc(h1g + (long)((u + 1) & 1) * GS +
                         (long)srow * SS + sg0 + shalf * 8, v);
                if (dec) {
                    short8 w = *(const short8*)(myTileT + srow * 16 + shalf * 8);
                    st128_cc(tsg + (long)(d & 1) * GS +
                             (long)srow * SS + sg0 + shalf * 8, w);
                    *(short8*)(temps + (long)d * (BB * SS) +
                               (long)(b0g + srow) * SS + sg0 + shalf * 8) = w;
                }
            }
            vm_drain();
            set_flag(f1 + myflag * 16, u + 1);
        }
    }
}

// ---------------------------------------------------------------------------
// frames epilogue (parallel, MFMA): per batch b,
//   P[e][c] = temp(e)[b] . Ws[c];  frames[b][e][c] = x_last + cumsum(P + bs)
// ---------------------------------------------------------------------------
__global__ __launch_bounds__(256) void frames_kernel(
    const u16* __restrict__ temps, const float* __restrict__ x,
    const u16* __restrict__ wsb, const float* __restrict__ bs,
    float* __restrict__ outp)
{
    const int b = blockIdx.x, tid = threadIdx.x;
    const int wave = tid >> 6, lane = tid & 63;
    const int l15 = lane & 15, quad = lane >> 4;
    __shared__ float P[64][81];

    const int e0 = wave * 16;
    floatx4 acc[5];
#pragma unroll
    for (int ct = 0; ct < 5; ++ct) acc[ct] = (floatx4){0.f, 0.f, 0.f, 0.f};
    const u16* aBase =
        temps + (long)(e0 + l15) * (BB * SS) + (long)b * SS + quad * 8;
#pragma unroll
    for (int kc = 0; kc < 16; ++kc) {
        short8 a = *(const short8*)(aBase + kc * 32);
#pragma unroll
        for (int ct = 0; ct < 5; ++ct) {
            const u16* wp = wsb + (long)(ct * 16 + l15) * SS + quad * 8 + kc * 32;
            MFMA_BF16(a, wp, acc[ct]);
        }
    }
#pragma unroll
    for (int ct = 0; ct < 5; ++ct)
#pragma unroll
        for (int r = 0; r < 4; ++r)
            P[e0 + quad * 4 + r][ct * 16 + l15] = acc[ct][r];
    __syncthreads();

    const int c = tid;
    if (c < CC) {
        float cum = x[((long)b * TT + (TT - 1)) * CC + c];
        const float bsv = bs[c];
        for (int e = 0; e < TT; ++e) {
            cum += P[e][c] + bsv;
            outp[(long)b * TT * CC + (long)e * CC + c] = cum;
        }
    }
}

// ---------------------------------------------------------------------------
extern "C" void kernel_launch(void* const* d_in, const int* in_sizes, int n_in,
                              void* d_out, int out_size, void* d_ws, size_t ws_size,
                              hipStream_t stream)
{
    const float* x    = (const float*)d_in[0];
    const float* Wih0 = (const float*)d_in[1];
    const float* Whh0 = (const float*)d_in[2];
    const float* bih0 = (const float*)d_in[3];
    const float* bhh0 = (const float*)d_in[4];
    const float* Wih1 = (const float*)d_in[5];
    const float* Whh1 = (const float*)d_in[6];
    const float* bih1 = (const float*)d_in[7];
    const float* bhh1 = (const float*)d_in[8];
    const float* Wt   = (const float*)d_in[9];
    const float* bt   = (const float*)d_in[10];
    const float* Ws   = (const float*)d_in[11];
    const float* bs   = (const float*)d_in[12];
    float* outp = (float*)d_out;

    char* p = (char*)d_ws;
    auto alloc = [&](size_t bytes) -> char* {
        char* r = p; p += (bytes + 255) & ~(size_t)255; return r;
    };
    u16* h0buf = (u16*)alloc((size_t)NGRP * 4 * GS * 2);
    u16* h1buf = (u16*)alloc((size_t)NGRP * 2 * GS * 2);
    u16* tstage = (u16*)alloc((size_t)NGRP * 2 * GS * 2);
    u16* xbf = (u16*)alloc((size_t)BB * TT * CPAD * 2);
    u16* wi0 = (u16*)alloc((size_t)NGATE * CPAD * 2);
    u16* wh0 = (u16*)alloc((size_t)NGATE * SS * 2);
    u16* wi1 = (u16*)alloc((size_t)NGATE * SS * 2);
    u16* wh1 = (u16*)alloc((size_t)NGATE * SS * 2);
    u16* Mbf = (u16*)alloc((size_t)NGATE * SS * 2);
    u16* wsb = (u16*)alloc((size_t)80 * SS * 2);
    float* c0vec = (float*)alloc((size_t)NGATE * 4);
    float* gi0i  = (float*)alloc((size_t)BB * NGATE * 4);
    u16* temps = (u16*)alloc((size_t)TT * BB * SS * 2);
    int* gflags = (int*)alloc((size_t)NGRP * 1024 * 4);

    hipMemsetAsync(h0buf, 0, (size_t)NGRP * 4 * GS * 2, stream);
    hipMemsetAsync(h1buf, 0, (size_t)NGRP * 2 * GS * 2, stream);
    hipMemsetAsync(gflags, 0, (size_t)NGRP * 1024 * 4, stream);

    prep1_kernel<<<1024, 256, 0, stream>>>(x, Wih0, Whh0, Wih1, Whh1, Ws,
                                           xbf, wi0, wh0, wi1, wh1, wsb);
    prep2_kernel<<<1024, 256, 0, stream>>>(x, Wih0, Ws, bs, Mbf, c0vec, gi0i);

    persist_kernel<<<NGRP * GBLK, 256, 0, stream>>>(
        xbf, wi0, wh0, wi1, wh1, Mbf, bih0, bhh0, bih1, bhh1,
        c0vec, gi0i, Wt, bt, h0buf, h1buf, tstage, temps, gflags);

    frames_kernel<<<BB, 256, 0, stream>>>(temps, x, wsb, bs, outp);
}